// Round 13
// baseline (336.613 us; speedup 1.0000x reference)
//
#include <hip/hip_runtime.h>
#include <hip/hip_bf16.h>
#include <stdint.h>

#define NN 4096
#define MAXNZ 1536   // cap on nnz per row of a2; /16 = 96 qchunks per row max
#define TCAP 8704    // pass-table capacity (qchunks); 34 KB LDS

// CSR entry format: (val << 20) | (col << 2).

// ---------------------------------------------------------------------------
// K1: scan_k — one coalesced pass over adj per row. Produces:
//   nbr (sorted neighbor list), deg, packed bit-adjacency abits (2 MB),
//   degree feats (cols 12..14). One wave per row.
// ---------------------------------------------------------------------------
__global__ __launch_bounds__(256) void scan_k(const float* __restrict__ adj,
                                              int* __restrict__ nbr,
                                              int* __restrict__ deg,
                                              unsigned long long* __restrict__ abits,
                                              float* __restrict__ feats) {
    __shared__ int nlist[4][64];
    int tid = threadIdx.x;
    int wv = tid >> 6, ln = tid & 63;
    int v = blockIdx.x * 4 + wv;
    size_t rb = (size_t)v * NN;
    int total = 0;
    unsigned long long myword = 0ull;
    for (int base = 0; base < NN; base += 64) {
        float val = adj[rb + base + ln];
        bool p = val > 0.5f;
        unsigned long long m = __ballot(p);
        if ((base >> 6) == ln) myword = m;
        if (p) {
            int pos = total + __popcll(m & ((1ull << ln) - 1ull));
            if (pos < 64) nlist[wv][pos] = base + ln;
        }
        total += __popcll(m);
    }
    abits[(size_t)v * 64 + ln] = myword;     // coalesced 8B/lane store
    int degL = min(total, 64);
    if (ln < degL) nbr[v * 64 + ln] = nlist[wv][ln];
    if (ln == 0) {
        deg[v] = total;
        float degf = (float)total;
        feats[v * 16 + 12] = degf;
        feats[v * 16 + 13] = degf * degf;
        feats[v * 16 + 14] = degf;           // diag(A^2) = deg (symmetric 0/1)
    }
}

// ---------------------------------------------------------------------------
// K2: cra2_k — role-split merged dispatch:
//   blocks [0, 4096):    a2 = adj@adj -> packed CSR (all-lane LDS scatter,
//                        stride-256 conflict-free extraction, pad to x16)
//   blocks [4096, 5120): cr_feat from the L2-resident bitmask (4 nodes/block)
// ---------------------------------------------------------------------------
__global__ __launch_bounds__(256) void cra2_k(const unsigned long long* __restrict__ abits,
                                              const int* __restrict__ nbr,
                                              const int* __restrict__ deg,
                                              unsigned int* __restrict__ csr,
                                              int* __restrict__ cnt,
                                              float* __restrict__ feats) {
    __shared__ __align__(16) unsigned int smem[NN + 132];
    int tid = threadIdx.x;
    int bid = blockIdx.x;
    int wv = tid >> 6, ln = tid & 63;

    if (bid < NN) {
        // ------------------- a2 role -------------------
        unsigned int* acc = smem;
        int* us  = (int*)(smem + NN + 1);
        int* dus = (int*)(smem + NN + 66);
        int v = bid;
        for (int j = tid; j < NN; j += 256) acc[j] = 0u;
        if (tid == 0) smem[NN] = 0u;
        int dv = min(deg[v], 64);
        if (tid < dv) {
            int u = nbr[v * 64 + tid];
            us[tid] = u;
            dus[tid] = min(deg[u], 64);
        }
        __syncthreads();
        for (int p = tid; p < dv * 64; p += 256) {
            int i = p >> 6, wi = p & 63;
            int u = us[i];
            if (wi < dus[i]) atomicAdd(&acc[nbr[u * 64 + wi]], 1u);
        }
        __syncthreads();
        unsigned int local = 0;
        #pragma unroll
        for (int m = 0; m < 16; m++) local += (acc[tid + 256 * m] != 0u);
        unsigned int pos = atomicAdd(&smem[NN], local);
        unsigned int* dst = csr + (size_t)v * MAXNZ;
        #pragma unroll
        for (int m = 0; m < 16; m++) {
            unsigned int a = acc[tid + 256 * m];
            if (a) {
                if (pos < 1520u) dst[pos] = (a << 20) | ((unsigned int)(tid + 256 * m) << 2);
                pos++;
            }
        }
        __syncthreads();
        unsigned int bs = min(smem[NN], 1520u);
        unsigned int padto = (bs + 15u) & ~15u;
        if (tid < padto - bs) dst[bs + tid] = (bs + tid) << 2;   // val=0, distinct col
        if (tid == 0) cnt[v] = (int)bs;
    } else {
        // ------------------- cr role -------------------
        unsigned long long* rows = (unsigned long long*)smem;   // [4][64], 2 KB
        int* mems = (int*)(smem + 1024);                        // [4][64], 1 KB
        int v = (bid - NN) * 4 + wv;

        int dv = deg[v];
        int degL = min(dv, 64);
        int c = min(dv + 1, 64);

        int nl = (ln < degL) ? nbr[v * 64 + ln] : 0;
        int isless = (ln < degL && nl < v) ? 1 : 0;
        int pos = isless;
        #pragma unroll
        for (int off = 32; off; off >>= 1) pos += __shfl_xor(pos, off, 64);

        int mem = 0;
        if (ln < c) {
            if (ln < pos)       mem = nl;
            else if (ln == pos) mem = v;
            else                mem = nbr[v * 64 + ln - 1];
        }
        mems[wv * 64 + ln] = mem;
        __syncthreads();

        unsigned long long mask = 0ull;
        {
            const unsigned long long* rowb = abits + (size_t)mem * 64;
            for (int j = 0; j < c; j++) {
                int mj = mems[wv * 64 + j];
                unsigned long long w = rowb[mj >> 6];
                mask |= ((w >> (mj & 63)) & 1ull) << j;
            }
        }
        if (ln >= c) mask = 0ull;
        rows[wv * 64 + ln] = mask;
        __syncthreads();

        int tpart = 0;
        float epart = 0.f, wpart = 0.f;
        if (ln < c) {
            unsigned long long mm = mask;
            while (mm) {
                int j = __ffsll(mm) - 1;
                mm &= mm - 1;
                tpart += __popcll(mask & rows[wv * 64 + j]);
            }
            if (ln != pos) {
                int cn = __popcll(rows[wv * 64 + pos] & mask);
                float D = (float)cn + 1.0f;
                epart = D;
                wpart = D * (D - 1.0f) * 0.5f;
            }
        }
        float es = epart, wsum2 = wpart;
        int ts = tpart;
        #pragma unroll
        for (int off = 32; off; off >>= 1) {
            es += __shfl_xor(es, off, 64);
            wsum2 += __shfl_xor(wsum2, off, 64);
            ts += __shfl_xor(ts, off, 64);
        }

        if (ln == 0) {
            float degf = (float)dv;
            float k = degf + 1.0f;
            float E = 0.5f * (es + degf);
            float W = wsum2 + degf * (degf - 1.0f) * 0.5f;
            float T = (float)ts / 6.0f;
            float f3 = T;
            float f2 = W - 3.0f * T;
            float f1 = E * (k - 2.0f) - 2.0f * f2 - 3.0f * f3;
            float tot = k * (k - 1.0f) * (k - 2.0f) / 6.0f;
            float f0 = tot - f1 - f2 - f3;
            if (k < 3.0f) { f0 = f1 = f2 = f3 = 0.f; }
            float s = f0 + f1 + f2 + f3 + 1e-10f;
            feats[v * 16 + 0] = f0 / s;
            feats[v * 16 + 1] = f1 / s;
            feats[v * 16 + 2] = f2 / s;
            feats[v * 16 + 3] = f3 / s;
        }
    }
}

// ---------------------------------------------------------------------------
// K3: fused sparse a4-row + top-8 + embedding — TABLE-DRIVEN FLAT QUEUE.
// Staging: shfl prefix-scan over per-entry qchunk counts (qchunk = 16 elems
// = 64 B), then each thread scatter-writes its entries' pass descriptors
// table[pos] = (u*96 + j) | (w<<21). Consumer: one LDS read -> one
// independent 64B load -> 16 ds_adds. No search, no select chain; loads
// pipeline freely. Pad entries (w=0) get nc=0. 512 thr / 8 waves / row.
// ---------------------------------------------------------------------------
__device__ __forceinline__ void do4(unsigned int* acc, uint4 E, unsigned int W) {
    atomicAdd(&acc[(E.x >> 2) & 0xFFFu], W * (E.x >> 20));
    atomicAdd(&acc[(E.y >> 2) & 0xFFFu], W * (E.y >> 20));
    atomicAdd(&acc[(E.z >> 2) & 0xFFFu], W * (E.z >> 20));
    atomicAdd(&acc[(E.w >> 2) & 0xFFFu], W * (E.w >> 20));
}

__global__ __launch_bounds__(512) void a4row_k(const unsigned int* __restrict__ csr,
                                               const int* __restrict__ cnt,
                                               const float* __restrict__ feats,
                                               const float* __restrict__ e_w,
                                               const float* __restrict__ e_b,
                                               float* __restrict__ x0) {
    __shared__ unsigned int acc[NN];            // 16 KB
    __shared__ unsigned int table[TCAP];        // 34 KB pass descriptors
    __shared__ unsigned int wsum[8];
    __shared__ unsigned int wtops[64];
    int tid = threadIdx.x;
    int wv = tid >> 6, ln = tid & 63;
    int v = blockIdx.x;

    for (int j = tid; j < NN; j += 512) acc[j] = 0u;

    int nv = cnt[v];
    const unsigned int* rowv = csr + (size_t)v * MAXNZ;

    // stage: thread t owns entries 3t..3t+2; per entry, qchunk count + sel
    unsigned int mync[3], mysel[3];
    #pragma unroll
    for (int k = 0; k < 3; k++) {
        int i = tid * 3 + k;
        unsigned int ncv = 0, sl = 0;
        if (i < nv) {
            unsigned int e = rowv[i];
            unsigned int u = (e >> 2) & 0xFFFu;
            unsigned int w = e >> 20;
            if (w) {
                ncv = ((unsigned int)cnt[u] + 15u) >> 4;    // qchunks
                sl = (u * 96u) | (w << 21);
            }
        }
        mync[k] = ncv;
        mysel[k] = sl;
    }
    unsigned int s012 = mync[0] + mync[1] + mync[2];
    // wave-inclusive scan of per-thread sums
    unsigned int incl = s012;
    #pragma unroll
    for (int off = 1; off < 64; off <<= 1) {
        unsigned int n = (unsigned int)__shfl_up((int)incl, off, 64);
        if (ln >= off) incl += n;
    }
    if (ln == 63) wsum[wv] = incl;
    __syncthreads();
    unsigned int wprefix = 0, tot = 0;
    #pragma unroll
    for (int q = 0; q < 8; q++) {
        unsigned int s = wsum[q];
        if (q < wv) wprefix += s;
        tot += s;
    }
    unsigned int b = wprefix + (incl - s012);
    #pragma unroll
    for (int k = 0; k < 3; k++) {
        unsigned int nc = mync[k];
        unsigned int sl = mysel[k];
        for (unsigned int j = 0; j < nc; j++) {
            unsigned int pos = b + j;
            if (pos < TCAP) table[pos] = sl + j;   // low bits: u*96+j qchunk idx
        }
        b += nc;
    }
    __syncthreads();

    int totq = (int)min(tot, (unsigned int)TCAP);
    const uint4* csr4 = (const uint4*)csr;
    for (int t = tid; t < totq; t += 512) {
        unsigned int sel = table[t];
        const uint4* p = csr4 + ((sel & 0xFFFFFu) << 2);
        uint4 E0 = p[0];
        uint4 E1 = p[1];
        uint4 E2 = p[2];
        uint4 E3 = p[3];
        unsigned int W = sel >> 21;
        do4(acc, E0, W);
        do4(acc, E1, W);
        do4(acc, E2, W);
        do4(acc, E3, W);
    }
    __syncthreads();

    // per-thread top-8 over 8 conflict-free LDS reads
    unsigned int best[8];
    #pragma unroll
    for (int q = 0; q < 8; q++) best[q] = 0u;
    #pragma unroll
    for (int m = 0; m < 8; m++) {
        unsigned int val = acc[tid + 512 * m];
        if (val > best[7]) {
            best[7] = val;
            #pragma unroll
            for (int s = 7; s > 0; s--) {
                if (best[s] > best[s - 1]) {
                    unsigned int t2 = best[s - 1]; best[s - 1] = best[s]; best[s] = t2;
                } else break;
            }
        }
    }

    // per-wave extract of 8 maxima (shfl-only)
    unsigned int wave_val = 0u;
    #pragma unroll
    for (int r = 0; r < 8; r++) {
        unsigned int m = best[0];
        #pragma unroll
        for (int off = 32; off; off >>= 1)
            m = max(m, (unsigned int)__shfl_xor((int)m, off, 64));
        unsigned long long bb = __ballot(best[0] == m);
        int src = __ffsll(bb) - 1;
        if (ln == src) {
            #pragma unroll
            for (int s = 0; s < 7; s++) best[s] = best[s + 1];
            best[7] = 0u;
        }
        if (ln == r) wave_val = m;
    }
    if (ln < 8) wtops[wv * 8 + ln] = wave_val;
    __syncthreads();

    // wave 0: merge 64 candidates, then fused embedding
    if (wv == 0) {
        unsigned int cand = wtops[ln];
        unsigned int myv = 0u;
        #pragma unroll
        for (int r = 0; r < 8; r++) {
            unsigned int m = cand;
            #pragma unroll
            for (int off = 32; off; off >>= 1)
                m = max(m, (unsigned int)__shfl_xor((int)m, off, 64));
            unsigned long long bb = __ballot(cand == m);
            int src = __ffsll(bb) - 1;
            if (ln == src) cand = 0u;
            if (ln == r) myv = m;
        }
        int d = ln;
        float s = e_b[d];
        s += feats[v * 16 + 0]  * e_w[0 * 64 + d];
        s += feats[v * 16 + 1]  * e_w[1 * 64 + d];
        s += feats[v * 16 + 2]  * e_w[2 * 64 + d];
        s += feats[v * 16 + 3]  * e_w[3 * 64 + d];
        #pragma unroll
        for (int j = 0; j < 8; j++) {
            float mj = (float)(unsigned int)__shfl((int)myv, j, 64);
            s += mj * e_w[(4 + j) * 64 + d];
        }
        s += feats[v * 16 + 12] * e_w[12 * 64 + d];
        s += feats[v * 16 + 13] * e_w[13 * 64 + d];
        s += feats[v * 16 + 14] * e_w[14 * 64 + d];
        x0[(size_t)v * 64 + d] = s;
    }
}

// ---------------------------------------------------------------------------
// K4: one GNN layer. For li==2, accumulate block column sums directly into
// out[64] via fp32 atomics (out pre-zeroed by hipMemsetAsync).
// ---------------------------------------------------------------------------
__global__ __launch_bounds__(256) void layer_k(const float* __restrict__ xin,
                                               float* __restrict__ xout,
                                               const float* __restrict__ w1,
                                               const float* __restrict__ b1,
                                               const float* __restrict__ w2,
                                               const float* __restrict__ b2,
                                               const float* __restrict__ eps,
                                               const int* __restrict__ nbr,
                                               const int* __restrict__ deg,
                                               float* __restrict__ out,
                                               int li) {
    __shared__ float h[4][64], t[4][64];
    int tid = threadIdx.x;
    int wv = tid >> 6, d = tid & 63;
    int v = blockIdx.x * 4 + wv;
    float xv = xin[(size_t)v * 64 + d];
    int dv = min(deg[v], 64);
    const int* nl = nbr + v * 64;
    float agg = 0.f;
    int j = 0;
    for (; j + 4 <= dv; j += 4) {
        int n0 = nl[j], n1 = nl[j + 1], n2 = nl[j + 2], n3 = nl[j + 3];
        float a0 = xin[(size_t)n0 * 64 + d];
        float a1 = xin[(size_t)n1 * 64 + d];
        float a2v = xin[(size_t)n2 * 64 + d];
        float a3 = xin[(size_t)n3 * 64 + d];
        agg += (a0 + a1) + (a2v + a3);
    }
    for (; j < dv; j++) agg += xin[(size_t)nl[j] * 64 + d];
    float hv = (1.0f + eps[li]) * xv + agg;
    h[wv][d] = hv;
    __syncthreads();
    float s = b1[li * 64 + d];
    #pragma unroll 8
    for (int k = 0; k < 64; k++) s += h[wv][k] * w1[li * 4096 + k * 64 + d];
    s = fmaxf(s, 0.f);
    t[wv][d] = s;
    __syncthreads();
    float o = b2[li * 64 + d];
    #pragma unroll 8
    for (int k = 0; k < 64; k++) o += t[wv][k] * w2[li * 4096 + k * 64 + d];
    if (li == 2) {
        h[wv][d] = o;
        __syncthreads();
        if (wv == 0)
            atomicAdd(&out[d], (h[0][d] + h[1][d]) + (h[2][d] + h[3][d]));
    } else {
        xout[(size_t)v * 64 + d] = o;
    }
}

// ---------------------------------------------------------------------------
extern "C" void kernel_launch(void* const* d_in, const int* in_sizes, int n_in,
                              void* d_out, int out_size, void* d_ws, size_t ws_size,
                              hipStream_t stream) {
    const float* adj = (const float*)d_in[0];
    const float* e_w = (const float*)d_in[1];
    const float* e_b = (const float*)d_in[2];
    const float* w1  = (const float*)d_in[3];
    const float* b1  = (const float*)d_in[4];
    const float* w2  = (const float*)d_in[5];
    const float* b2  = (const float*)d_in[6];
    const float* eps = (const float*)d_in[7];
    float* out = (float*)d_out;

    char* ws = (char*)d_ws;
    unsigned int*       csr     = (unsigned int*)(ws);                  // 24 MB
    int*                nbr     = (int*)(ws + 25165824);                // 1 MB
    int*                deg     = (int*)(ws + 26214400);                // 16 KB
    int*                cnt     = (int*)(ws + 26230784);                // 16 KB
    float*              feats   = (float*)(ws + 26247168);              // 256 KB
    float*              x0      = (float*)(ws + 26509312);              // 1 MB
    float*              x1      = (float*)(ws + 27557888);              // 1 MB
    unsigned long long* abits   = (unsigned long long*)(ws + 28868608); // 2 MB

    hipMemsetAsync(out, 0, 64 * sizeof(float), stream);
    scan_k<<<1024, 256, 0, stream>>>(adj, nbr, deg, abits, feats);
    cra2_k<<<5120, 256, 0, stream>>>(abits, nbr, deg, csr, cnt, feats);
    a4row_k<<<4096, 512, 0, stream>>>(csr, cnt, feats, e_w, e_b, x0);
    layer_k<<<1024, 256, 0, stream>>>(x0, x1, w1, b1, w2, b2, eps, nbr, deg, out, 0);
    layer_k<<<1024, 256, 0, stream>>>(x1, x0, w1, b1, w2, b2, eps, nbr, deg, out, 1);
    layer_k<<<1024, 256, 0, stream>>>(x0, x1, w1, b1, w2, b2, eps, nbr, deg, out, 2);
}

// Round 14
// 301.565 us; speedup vs baseline: 1.1162x; 1.1162x over previous
//
#include <hip/hip_runtime.h>
#include <hip/hip_bf16.h>
#include <stdint.h>

#define NN 4096
#define MAXNZ 1536   // cap on nnz per row of a2; pad to x16; /8 = 192 dchunks

// CSR entry format: (val << 20) | (col << 2).

// ---------------------------------------------------------------------------
// K1: scan_k — one pass over adj per row, 4x-unrolled (4 independent wave
// loads in flight before the ballots consume them). Produces nbr, deg,
// bit-adjacency abits (2 MB), degree feats.
// ---------------------------------------------------------------------------
__global__ __launch_bounds__(256) void scan_k(const float* __restrict__ adj,
                                              int* __restrict__ nbr,
                                              int* __restrict__ deg,
                                              unsigned long long* __restrict__ abits,
                                              float* __restrict__ feats) {
    __shared__ int nlist[4][64];
    int tid = threadIdx.x;
    int wv = tid >> 6, ln = tid & 63;
    int v = blockIdx.x * 4 + wv;
    size_t rb = (size_t)v * NN;
    int total = 0;
    unsigned long long w0 = 0, w1 = 0, w2 = 0, w3 = 0;
    for (int base = 0; base < NN; base += 256) {
        float v0 = adj[rb + base + ln];
        float v1 = adj[rb + base + 64 + ln];
        float v2 = adj[rb + base + 128 + ln];
        float v3 = adj[rb + base + 192 + ln];
        int q = base >> 8;   // 0..15
        {
            unsigned long long m = __ballot(v0 > 0.5f);
            if ((q & 3) == 0 && (ln >> 2) == q) w0 = w0; // keep regs alive
            if (v0 > 0.5f) {
                int pos = total + __popcll(m & ((1ull << ln) - 1ull));
                if (pos < 64) nlist[wv][pos] = base + ln;
            }
            if ((q << 2) + 0 == (ln & 63)) w0 = m;
            total += __popcll(m);
            if (v0 > 0.5f) {} // no-op
            // save word index (base/64) = q*4+0 -> lane q*4+0
            if (ln == (q << 2) + 0) w1 = w1;
            (void)m;
        }
        // NOTE: the above saves word q*4+0 into w0 only when lane matches;
        // handle all four sub-blocks uniformly below instead.
        {
            unsigned long long m = __ballot(v1 > 0.5f);
            if (v1 > 0.5f) {
                int pos = total + __popcll(m & ((1ull << ln) - 1ull));
                if (pos < 64) nlist[wv][pos] = base + 64 + ln;
            }
            if (ln == (q << 2) + 1) w0 = m;
            total += __popcll(m);
        }
        {
            unsigned long long m = __ballot(v2 > 0.5f);
            if (v2 > 0.5f) {
                int pos = total + __popcll(m & ((1ull << ln) - 1ull));
                if (pos < 64) nlist[wv][pos] = base + 128 + ln;
            }
            if (ln == (q << 2) + 2) w0 = m;
            total += __popcll(m);
        }
        {
            unsigned long long m = __ballot(v3 > 0.5f);
            if (v3 > 0.5f) {
                int pos = total + __popcll(m & ((1ull << ln) - 1ull));
                if (pos < 64) nlist[wv][pos] = base + 192 + ln;
            }
            if (ln == (q << 2) + 3) w0 = m;
            total += __popcll(m);
        }
        // word q*4+0 goes to lane q*4+0: redo first sub-block save correctly
        // (the first block above saved only a placeholder)
    }
    // Recompute word for sub-block 0 lanes: lane ln needs word ln = ballot of
    // columns [ln*64, ln*64+64). Sub-block-0 words are lanes ln%4==0 — they
    // were not saved in the messy first block; fix with a second mini-pass
    // over just those 16 words (16 loads + 16 ballots).
    for (int qq = 0; qq < 16; qq++) {
        int base = qq * 256;
        float vv = adj[rb + base + ln];
        unsigned long long m = __ballot(vv > 0.5f);
        if (ln == (qq << 2)) w0 = m;
    }
    abits[(size_t)v * 64 + ln] = w0;
    int degL = min(total, 64);
    if (ln < degL) nbr[v * 64 + ln] = nlist[wv][ln];
    if (ln == 0) {
        deg[v] = total;
        float degf = (float)total;
        feats[v * 16 + 12] = degf;
        feats[v * 16 + 13] = degf * degf;
        feats[v * 16 + 14] = degf;           // diag(A^2) = deg (symmetric 0/1)
    }
}

// ---------------------------------------------------------------------------
// K2: cra2_k — role-split merged dispatch:
//   blocks [0, 4096):    a2 = adj@adj -> packed CSR (all-lane LDS scatter,
//                        stride-256 conflict-free extraction, pad to x16)
//   blocks [4096, 5120): cr_feat from the L2-resident bitmask (4 nodes/block)
// ---------------------------------------------------------------------------
__global__ __launch_bounds__(256) void cra2_k(const unsigned long long* __restrict__ abits,
                                              const int* __restrict__ nbr,
                                              const int* __restrict__ deg,
                                              unsigned int* __restrict__ csr,
                                              int* __restrict__ cnt,
                                              float* __restrict__ feats) {
    __shared__ __align__(16) unsigned int smem[NN + 132];
    int tid = threadIdx.x;
    int bid = blockIdx.x;
    int wv = tid >> 6, ln = tid & 63;

    if (bid < NN) {
        // ------------------- a2 role -------------------
        unsigned int* acc = smem;
        int* us  = (int*)(smem + NN + 1);
        int* dus = (int*)(smem + NN + 66);
        int v = bid;
        for (int j = tid; j < NN; j += 256) acc[j] = 0u;
        if (tid == 0) smem[NN] = 0u;
        int dv = min(deg[v], 64);
        if (tid < dv) {
            int u = nbr[v * 64 + tid];
            us[tid] = u;
            dus[tid] = min(deg[u], 64);
        }
        __syncthreads();
        for (int p = tid; p < dv * 64; p += 256) {
            int i = p >> 6, wi = p & 63;
            int u = us[i];
            if (wi < dus[i]) atomicAdd(&acc[nbr[u * 64 + wi]], 1u);
        }
        __syncthreads();
        unsigned int local = 0;
        #pragma unroll
        for (int m = 0; m < 16; m++) local += (acc[tid + 256 * m] != 0u);
        unsigned int pos = atomicAdd(&smem[NN], local);
        unsigned int* dst = csr + (size_t)v * MAXNZ;
        #pragma unroll
        for (int m = 0; m < 16; m++) {
            unsigned int a = acc[tid + 256 * m];
            if (a) {
                if (pos < 1520u) dst[pos] = (a << 20) | ((unsigned int)(tid + 256 * m) << 2);
                pos++;
            }
        }
        __syncthreads();
        unsigned int bs = min(smem[NN], 1520u);
        unsigned int padto = (bs + 15u) & ~15u;
        if (tid < padto - bs) dst[bs + tid] = (bs + tid) << 2;   // val=0, distinct col
        if (tid == 0) cnt[v] = (int)bs;
    } else {
        // ------------------- cr role -------------------
        unsigned long long* rows = (unsigned long long*)smem;   // [4][64], 2 KB
        int* mems = (int*)(smem + 1024);                        // [4][64], 1 KB
        int v = (bid - NN) * 4 + wv;

        int dv = deg[v];
        int degL = min(dv, 64);
        int c = min(dv + 1, 64);

        int nl = (ln < degL) ? nbr[v * 64 + ln] : 0;
        int isless = (ln < degL && nl < v) ? 1 : 0;
        int pos = isless;
        #pragma unroll
        for (int off = 32; off; off >>= 1) pos += __shfl_xor(pos, off, 64);

        int mem = 0;
        if (ln < c) {
            if (ln < pos)       mem = nl;
            else if (ln == pos) mem = v;
            else                mem = nbr[v * 64 + ln - 1];
        }
        mems[wv * 64 + ln] = mem;
        __syncthreads();

        unsigned long long mask = 0ull;
        {
            const unsigned long long* rowb = abits + (size_t)mem * 64;
            for (int j = 0; j < c; j++) {
                int mj = mems[wv * 64 + j];
                unsigned long long w = rowb[mj >> 6];
                mask |= ((w >> (mj & 63)) & 1ull) << j;
            }
        }
        if (ln >= c) mask = 0ull;
        rows[wv * 64 + ln] = mask;
        __syncthreads();

        int tpart = 0;
        float epart = 0.f, wpart = 0.f;
        if (ln < c) {
            unsigned long long mm = mask;
            while (mm) {
                int j = __ffsll(mm) - 1;
                mm &= mm - 1;
                tpart += __popcll(mask & rows[wv * 64 + j]);
            }
            if (ln != pos) {
                int cn = __popcll(rows[wv * 64 + pos] & mask);
                float D = (float)cn + 1.0f;
                epart = D;
                wpart = D * (D - 1.0f) * 0.5f;
            }
        }
        float es = epart, wsum2 = wpart;
        int ts = tpart;
        #pragma unroll
        for (int off = 32; off; off >>= 1) {
            es += __shfl_xor(es, off, 64);
            wsum2 += __shfl_xor(wsum2, off, 64);
            ts += __shfl_xor(ts, off, 64);
        }

        if (ln == 0) {
            float degf = (float)dv;
            float k = degf + 1.0f;
            float E = 0.5f * (es + degf);
            float W = wsum2 + degf * (degf - 1.0f) * 0.5f;
            float T = (float)ts / 6.0f;
            float f3 = T;
            float f2 = W - 3.0f * T;
            float f1 = E * (k - 2.0f) - 2.0f * f2 - 3.0f * f3;
            float tot = k * (k - 1.0f) * (k - 2.0f) / 6.0f;
            float f0 = tot - f1 - f2 - f3;
            if (k < 3.0f) { f0 = f1 = f2 = f3 = 0.f; }
            float s = f0 + f1 + f2 + f3 + 1e-10f;
            feats[v * 16 + 0] = f0 / s;
            feats[v * 16 + 1] = f1 / s;
            feats[v * 16 + 2] = f2 / s;
            feats[v * 16 + 3] = f3 / s;
        }
    }
}

// ---------------------------------------------------------------------------
// K3: fused sparse a4-row + top-8 + embedding — round-10 structure (best
// measured: 122 µs). Double-chunk passes (8 elems/lane), 4-way entry fusion
// with pre-biased packed selects, shfl-only top-8 (2 barriers).
// ---------------------------------------------------------------------------
__device__ __forceinline__ void do4(unsigned int* acc, uint4 E, unsigned int W) {
    atomicAdd(&acc[(E.x >> 2) & 0xFFFu], W * (E.x >> 20));
    atomicAdd(&acc[(E.y >> 2) & 0xFFFu], W * (E.y >> 20));
    atomicAdd(&acc[(E.z >> 2) & 0xFFFu], W * (E.z >> 20));
    atomicAdd(&acc[(E.w >> 2) & 0xFFFu], W * (E.w >> 20));
}

__global__ __launch_bounds__(512) void a4row_k(const unsigned int* __restrict__ csr,
                                               const int* __restrict__ cnt,
                                               const float* __restrict__ feats,
                                               const float* __restrict__ e_w,
                                               const float* __restrict__ e_b,
                                               float* __restrict__ x0) {
    __shared__ unsigned int acc[NN];                       // 16 KB
    __shared__ __align__(16) unsigned int rowe[MAXNZ];     // 6 KB
    __shared__ unsigned int wtops[64];
    int tid = threadIdx.x;
    int wv = tid >> 6, ln = tid & 63;
    int v = blockIdx.x;

    for (int j = tid; j < NN; j += 512) acc[j] = 0u;

    int nv = cnt[v];
    int nvp = (nv + 7) & ~7;
    const unsigned int* rowv = csr + (size_t)v * MAXNZ;
    for (int i = tid; i < nvp; i += 512) {
        unsigned int e = rowv[i];
        unsigned int u = (e >> 2) & 0xFFFu;
        unsigned int w = e >> 20;
        unsigned int nc = w ? (((unsigned int)cnt[u] + 7u) >> 3) : 0u; // dchunks
        rowe[i] = u | (w << 12) | (nc << 19);
    }
    __syncthreads();

    const uint4* csr4 = (const uint4*)csr;
    for (int i0 = wv * 4; i0 < nvp; i0 += 32) {
        uint4 q = *(const uint4*)&rowe[i0];
        int c1 = (int)(q.x >> 19);
        int c2 = c1 + (int)(q.y >> 19);
        int c3 = c2 + (int)(q.z >> 19);
        int tot = c3 + (int)(q.w >> 19);
        unsigned int s0 = ((q.x & 0xFFFu) * 192u + 1024u)                    | (((q.x >> 12) & 0x7Fu) << 21);
        unsigned int s1 = ((q.y & 0xFFFu) * 192u + 1024u - (unsigned int)c1) | (((q.y >> 12) & 0x7Fu) << 21);
        unsigned int s2 = ((q.z & 0xFFFu) * 192u + 1024u - (unsigned int)c2) | (((q.z >> 12) & 0x7Fu) << 21);
        unsigned int s3 = ((q.w & 0xFFFu) * 192u + 1024u - (unsigned int)c3) | (((q.w >> 12) & 0x7Fu) << 21);
        for (int g = ln; g < tot; g += 64) {
            unsigned int sel = (g < c1) ? s0 : ((g < c2) ? s1 : ((g < c3) ? s2 : s3));
            unsigned int d2 = ((sel & 0x1FFFFFu) + (unsigned int)g - 1024u) << 1;
            const uint4* p = csr4 + d2;
            uint4 E0 = p[0];
            uint4 E1 = p[1];
            unsigned int W = sel >> 21;
            do4(acc, E0, W);
            do4(acc, E1, W);
        }
    }
    __syncthreads();

    // per-thread top-8 over 8 conflict-free LDS reads
    unsigned int best[8];
    #pragma unroll
    for (int q = 0; q < 8; q++) best[q] = 0u;
    #pragma unroll
    for (int m = 0; m < 8; m++) {
        unsigned int val = acc[tid + 512 * m];
        if (val > best[7]) {
            best[7] = val;
            #pragma unroll
            for (int s = 7; s > 0; s--) {
                if (best[s] > best[s - 1]) {
                    unsigned int t2 = best[s - 1]; best[s - 1] = best[s]; best[s] = t2;
                } else break;
            }
        }
    }

    // per-wave extract of 8 maxima (shfl-only)
    unsigned int wave_val = 0u;
    #pragma unroll
    for (int r = 0; r < 8; r++) {
        unsigned int m = best[0];
        #pragma unroll
        for (int off = 32; off; off >>= 1)
            m = max(m, (unsigned int)__shfl_xor((int)m, off, 64));
        unsigned long long bb = __ballot(best[0] == m);
        int src = __ffsll(bb) - 1;
        if (ln == src) {
            #pragma unroll
            for (int s = 0; s < 7; s++) best[s] = best[s + 1];
            best[7] = 0u;
        }
        if (ln == r) wave_val = m;
    }
    if (ln < 8) wtops[wv * 8 + ln] = wave_val;
    __syncthreads();

    // wave 0: merge 64 candidates, then fused embedding
    if (wv == 0) {
        unsigned int cand = wtops[ln];
        unsigned int myv = 0u;
        #pragma unroll
        for (int r = 0; r < 8; r++) {
            unsigned int m = cand;
            #pragma unroll
            for (int off = 32; off; off >>= 1)
                m = max(m, (unsigned int)__shfl_xor((int)m, off, 64));
            unsigned long long bb = __ballot(cand == m);
            int src = __ffsll(bb) - 1;
            if (ln == src) cand = 0u;
            if (ln == r) myv = m;
        }
        int d = ln;
        float s = e_b[d];
        s += feats[v * 16 + 0]  * e_w[0 * 64 + d];
        s += feats[v * 16 + 1]  * e_w[1 * 64 + d];
        s += feats[v * 16 + 2]  * e_w[2 * 64 + d];
        s += feats[v * 16 + 3]  * e_w[3 * 64 + d];
        #pragma unroll
        for (int j = 0; j < 8; j++) {
            float mj = (float)(unsigned int)__shfl((int)myv, j, 64);
            s += mj * e_w[(4 + j) * 64 + d];
        }
        s += feats[v * 16 + 12] * e_w[12 * 64 + d];
        s += feats[v * 16 + 13] * e_w[13 * 64 + d];
        s += feats[v * 16 + 14] * e_w[14 * 64 + d];
        x0[(size_t)v * 64 + d] = s;
    }
}

// ---------------------------------------------------------------------------
// K4: one GNN layer. For li==2, accumulate block column sums directly into
// out[64] via fp32 atomics (out pre-zeroed by hipMemsetAsync).
// ---------------------------------------------------------------------------
__global__ __launch_bounds__(256) void layer_k(const float* __restrict__ xin,
                                               float* __restrict__ xout,
                                               const float* __restrict__ w1,
                                               const float* __restrict__ b1,
                                               const float* __restrict__ w2,
                                               const float* __restrict__ b2,
                                               const float* __restrict__ eps,
                                               const int* __restrict__ nbr,
                                               const int* __restrict__ deg,
                                               float* __restrict__ out,
                                               int li) {
    __shared__ float h[4][64], t[4][64];
    int tid = threadIdx.x;
    int wv = tid >> 6, d = tid & 63;
    int v = blockIdx.x * 4 + wv;
    float xv = xin[(size_t)v * 64 + d];
    int dv = min(deg[v], 64);
    const int* nl = nbr + v * 64;
    float agg = 0.f;
    int j = 0;
    for (; j + 4 <= dv; j += 4) {
        int n0 = nl[j], n1 = nl[j + 1], n2 = nl[j + 2], n3 = nl[j + 3];
        float a0 = xin[(size_t)n0 * 64 + d];
        float a1 = xin[(size_t)n1 * 64 + d];
        float a2v = xin[(size_t)n2 * 64 + d];
        float a3 = xin[(size_t)n3 * 64 + d];
        agg += (a0 + a1) + (a2v + a3);
    }
    for (; j < dv; j++) agg += xin[(size_t)nl[j] * 64 + d];
    float hv = (1.0f + eps[li]) * xv + agg;
    h[wv][d] = hv;
    __syncthreads();
    float s = b1[li * 64 + d];
    #pragma unroll 8
    for (int k = 0; k < 64; k++) s += h[wv][k] * w1[li * 4096 + k * 64 + d];
    s = fmaxf(s, 0.f);
    t[wv][d] = s;
    __syncthreads();
    float o = b2[li * 64 + d];
    #pragma unroll 8
    for (int k = 0; k < 64; k++) o += t[wv][k] * w2[li * 4096 + k * 64 + d];
    if (li == 2) {
        h[wv][d] = o;
        __syncthreads();
        if (wv == 0)
            atomicAdd(&out[d], (h[0][d] + h[1][d]) + (h[2][d] + h[3][d]));
    } else {
        xout[(size_t)v * 64 + d] = o;
    }
}

// ---------------------------------------------------------------------------
extern "C" void kernel_launch(void* const* d_in, const int* in_sizes, int n_in,
                              void* d_out, int out_size, void* d_ws, size_t ws_size,
                              hipStream_t stream) {
    const float* adj = (const float*)d_in[0];
    const float* e_w = (const float*)d_in[1];
    const float* e_b = (const float*)d_in[2];
    const float* w1  = (const float*)d_in[3];
    const float* b1  = (const float*)d_in[4];
    const float* w2  = (const float*)d_in[5];
    const float* b2  = (const float*)d_in[6];
    const float* eps = (const float*)d_in[7];
    float* out = (float*)d_out;

    char* ws = (char*)d_ws;
    unsigned int*       csr     = (unsigned int*)(ws);                  // 24 MB
    int*                nbr     = (int*)(ws + 25165824);                // 1 MB
    int*                deg     = (int*)(ws + 26214400);                // 16 KB
    int*                cnt     = (int*)(ws + 26230784);                // 16 KB
    float*              feats   = (float*)(ws + 26247168);              // 256 KB
    float*              x0      = (float*)(ws + 26509312);              // 1 MB
    float*              x1      = (float*)(ws + 27557888);              // 1 MB
    unsigned long long* abits   = (unsigned long long*)(ws + 28868608); // 2 MB

    hipMemsetAsync(out, 0, 64 * sizeof(float), stream);
    scan_k<<<1024, 256, 0, stream>>>(adj, nbr, deg, abits, feats);
    cra2_k<<<5120, 256, 0, stream>>>(abits, nbr, deg, csr, cnt, feats);
    a4row_k<<<4096, 512, 0, stream>>>(csr, cnt, feats, e_w, e_b, x0);
    layer_k<<<1024, 256, 0, stream>>>(x0, x1, w1, b1, w2, b2, eps, nbr, deg, out, 0);
    layer_k<<<1024, 256, 0, stream>>>(x1, x0, w1, b1, w2, b2, eps, nbr, deg, out, 1);
    layer_k<<<1024, 256, 0, stream>>>(x0, x1, w1, b1, w2, b2, eps, nbr, deg, out, 2);
}